// Round 1
// baseline (13103.091 us; speedup 1.0000x reference)
//
#include <hip/hip_runtime.h>
#include <math.h>

// GPNN: B=8 graphs, N=128 nodes, DV=512, DE=256, K=3, C=117.
// Strategy: hoist everything hoistable out of the sequential scan into
// parallel GEMM kernels; scan = 1 workgroup per batch maintaining G=W2@h in LDS.

#define NB 8
#define NN 128
#define DVV 512
#define DEE 256
#define NCC 117

__device__ __forceinline__ float sigmf(float x) { return 1.0f / (1.0f + expf(-x)); }

// ---------------- h init: h_buf[b][n][d] = node_features[b][n][d] ----------------
__global__ __launch_bounds__(256) void k_copy(const float* __restrict__ src, float* __restrict__ dst) {
  int i = blockIdx.x * 256 + threadIdx.x;          // grid covers exactly 131072 float4s
  ((float4*)dst)[i] = ((const float4*)src)[i];
}

// ---------------- weight transposes (once per call) ----------------
// dst[c][rows] = src[r*ld + off + c]
__global__ __launch_bounds__(256) void k_tr(const float* __restrict__ src, float* __restrict__ dst,
                                            int rows, int cols, int ld, int off) {
  int idx = blockIdx.x * 256 + threadIdx.x;
  if (idx >= rows * cols) return;
  int r = idx / cols, c = idx - r * cols;
  dst[(size_t)c * rows + r] = src[(size_t)r * ld + off + c];
}

// ---------------- ai/aj: av[b][0][n]=wl_j.h_n  av[b][1][n]=wl_i.h_n ----------------
__global__ __launch_bounds__(128) void k_av(const float* __restrict__ h, const float* __restrict__ w_link,
                                            float* __restrict__ av) {
  int b = blockIdx.x >> 7, n = blockIdx.x & 127;
  int lane = threadIdx.x & 63, half = threadIdx.x >> 6;
  const float* hc = h + (size_t)((b << 7) + n) * DVV;
  const float* w = w_link + half * DVV;
  float acc = 0.f;
#pragma unroll
  for (int t = 0; t < 8; ++t) { int d = lane + (t << 6); acc += w[d] * hc[d]; }
#pragma unroll
  for (int off = 32; off; off >>= 1) acc += __shfl_down(acc, off);
  if (lane == 0) av[(b << 8) + half * NN + n] = acc;
}

// ---------------- per-row: logitE[b][i][j] = sum_c wl_e[c]*e[c,i,j];  e_buf[b][i] <- P = W3 @ e_row ----------------
template <int FIRST>
__global__ __launch_bounds__(256) void k_plogit(const float* src, const float* __restrict__ w_msg,
                                                const float* __restrict__ w_link, float* e_buf,
                                                float* __restrict__ lE) {
  int b = blockIdx.x >> 7, i = blockIdx.x & 127;
  __shared__ __align__(16) float eL[DEE][132];   // [c][j], padded
  int tid = threadIdx.x;
  if (FIRST) {
    // edge_features[b][i][j][c]  (j,c) contiguous -> transpose into LDS
    const float* s0 = src + (size_t)(b * NN + i) * NN * DEE;
    for (int l = tid * 4; l < NN * DEE; l += 1024) {
      float4 v = *(const float4*)&s0[l];
      int c = l & 255, j = l >> 8;
      eL[c + 0][j] = v.x; eL[c + 1][j] = v.y; eL[c + 2][j] = v.z; eL[c + 3][j] = v.w;
    }
  } else {
    const float* s0 = src + (size_t)(b * NN + i) * DEE * NN;   // [c][j]
    for (int l = tid * 4; l < NN * DEE; l += 1024) {
      int c = l >> 7, j = l & 127;
      *(float4*)&eL[c][j] = *(const float4*)&s0[l];
    }
  }
  __syncthreads();
  if (tid < NN) {
    float acc = 0.f;
    for (int c = 0; c < DEE; ++c) acc += w_link[1024 + c] * eL[c][tid];
    lE[((size_t)b * NN + i) * NN + tid] = acc;
  }
  // P = W3 @ eL  (in place over e_buf row). 256 thr = 32 cgrp(8 rows) x 8 jgrp(16 cols)
  int cg = tid >> 3, s = tid & 7;
  int c0 = cg * 8, jb = s * 16;
  float acc[8][16];
#pragma unroll
  for (int r = 0; r < 8; ++r)
#pragma unroll
    for (int u = 0; u < 16; ++u) acc[r][u] = 0.f;
  for (int c = 0; c < DEE; c += 4) {
    float4 w[8];
#pragma unroll
    for (int r = 0; r < 8; ++r) w[r] = *(const float4*)&w_msg[(size_t)(c0 + r) * 1280 + 1024 + c];
#pragma unroll
    for (int cc = 0; cc < 4; ++cc) {
      float4 e0 = *(const float4*)&eL[c + cc][jb];
      float4 e1 = *(const float4*)&eL[c + cc][jb + 4];
      float4 e2 = *(const float4*)&eL[c + cc][jb + 8];
      float4 e3 = *(const float4*)&eL[c + cc][jb + 12];
#pragma unroll
      for (int r = 0; r < 8; ++r) {
        float wv = ((const float*)&w[r])[cc];
        acc[r][0] += wv * e0.x;  acc[r][1] += wv * e0.y;  acc[r][2] += wv * e0.z;  acc[r][3] += wv * e0.w;
        acc[r][4] += wv * e1.x;  acc[r][5] += wv * e1.y;  acc[r][6] += wv * e1.z;  acc[r][7] += wv * e1.w;
        acc[r][8] += wv * e2.x;  acc[r][9] += wv * e2.y;  acc[r][10] += wv * e2.z; acc[r][11] += wv * e2.w;
        acc[r][12] += wv * e3.x; acc[r][13] += wv * e3.y; acc[r][14] += wv * e3.z; acc[r][15] += wv * e3.w;
      }
    }
  }
#pragma unroll
  for (int r = 0; r < 8; ++r)
#pragma unroll
    for (int u4 = 0; u4 < 4; ++u4) {
      float4 o; o.x = acc[r][u4 * 4]; o.y = acc[r][u4 * 4 + 1]; o.z = acc[r][u4 * 4 + 2]; o.w = acc[r][u4 * 4 + 3];
      *(float4*)&e_buf[((size_t)(b * NN + i) * DEE + c0 + r) * NN + jb + u4 * 4] = o;
    }
}

// ---------------- adj = sigmoid(ai[i] + aj[j] + logitE + b_link) -> d_out[0:131072] ----------------
__global__ __launch_bounds__(256) void k_adj(const float* __restrict__ av, const float* __restrict__ lE,
                                             const float* __restrict__ b_link, float* __restrict__ out) {
  int idx = blockIdx.x * 256 + threadIdx.x;   // < 131072
  int b = idx >> 14, r = idx & 16383, i = r >> 7, j = r & 127;
  float x = av[(b << 8) + NN + i] + av[(b << 8) + j] + lE[idx] + b_link[0];
  out[idx] = sigmf(x);
}

// ---------------- generic out[b][n][R] = W(R x 512) @ h[b][:][n] (+bias) ----------------
__global__ __launch_bounds__(256) void k_wh(const float* __restrict__ W, int ldw, int R,
                                            const float* bias, const float* __restrict__ h,
                                            float* __restrict__ out) {
  int r0 = blockIdx.x * 16, b = blockIdx.y;
  __shared__ float hT[128][129];
  __shared__ float wT[16][129];
  __shared__ float outT[16][129];
  int tid = threadIdx.x;
  int n = tid & 127, rr = tid >> 7;
  float acc8[8] = {0, 0, 0, 0, 0, 0, 0, 0};
  for (int dc = 0; dc < DVV; dc += 128) {
    if (dc) __syncthreads();
    for (int l = tid * 4; l < 16384; l += 1024) {
      int nn = l >> 7, d = l & 127;
      float4 v = *(const float4*)&h[((size_t)(b << 7) + nn) * DVV + dc + d];
      hT[d + 0][nn] = v.x; hT[d + 1][nn] = v.y; hT[d + 2][nn] = v.z; hT[d + 3][nn] = v.w;
    }
    for (int l = tid; l < 2048; l += 256) {
      int r = l >> 7, d = l & 127;
      wT[r][d] = W[(size_t)(r0 + r) * ldw + dc + d];
    }
    __syncthreads();
    for (int d = 0; d < 128; ++d) {
      float hval = hT[d][n];
#pragma unroll
      for (int r8 = 0; r8 < 8; ++r8) acc8[r8] += wT[rr * 8 + r8][d] * hval;
    }
  }
#pragma unroll
  for (int r8 = 0; r8 < 8; ++r8) {
    int r = rr * 8 + r8;
    outT[r][n] = acc8[r8] + (bias ? bias[r0 + r] : 0.0f);
  }
  __syncthreads();
  int n2 = tid >> 1, q = tid & 1;
  size_t base = ((size_t)(b << 7) + n2) * R + r0 + q * 8;
  float4 o0; o0.x = outT[q * 8 + 0][n2]; o0.y = outT[q * 8 + 1][n2]; o0.z = outT[q * 8 + 2][n2]; o0.w = outT[q * 8 + 3][n2];
  float4 o1; o1.x = outT[q * 8 + 4][n2]; o1.y = outT[q * 8 + 5][n2]; o1.z = outT[q * 8 + 6][n2]; o1.w = outT[q * 8 + 7][n2];
  *(float4*)&out[base] = o0;
  *(float4*)&out[base + 4] = o1;
}

// ---------------- the sequential scan: 1 workgroup per batch ----------------
// eP: e_buf holding P rows (overwritten with m when WRITE_E)
// adj: d_out adj region; GH/U: [b][i][*]; Gini: [b][j][c']; h: [b][n][d]
// w_ihT: [c'][1536]; w2T: [d][256]
template <int WRITE_E>
__global__ __launch_bounds__(1024) void k_scan(float* eP, const float* __restrict__ adj,
                                               const float* __restrict__ GH, const float* __restrict__ U,
                                               const float* __restrict__ Gini, float* __restrict__ h,
                                               const float* __restrict__ w_ihT, const float* __restrict__ b_ih,
                                               const float* __restrict__ w2T) {
  int b = blockIdx.x;
  __shared__ __align__(16) float G[128][260];   // [j][c'], 133 KB
  __shared__ __align__(16) float ms[256];
  __shared__ float hv[512];
  __shared__ __align__(16) float hn[512];
  __shared__ float zb[512];
  __shared__ float adjrow[128];
  __shared__ float uu[256];
  int tid = threadIdx.x;

  for (int l = tid * 4; l < 32768; l += 4096) {
    float4 v = *(const float4*)&Gini[(size_t)b * 32768 + l];
    int j = l >> 8, c = l & 255;
    *(float4*)&G[j][c] = v;
  }

  const int cA = tid >> 2, sA = tid & 3;

  for (int i = 0; i < NN; ++i) {
    // preload step-i vectors
    if (tid < 128) adjrow[tid] = adj[((size_t)b * NN + i) * NN + tid];
    else if (tid < 384) uu[tid - 128] = U[((size_t)b * NN + i) * DEE + (tid - 128)];
    else if (tid < 896) hv[tid - 384] = h[((size_t)b * NN + i) * DVV + (tid - 384)];
    __syncthreads();   // also orders prev-step G-column write before phase A

    // ---- Phase A: m = relu(u + G + P), m_sum = m . adj_row, e <- m ----
    {
      float* Prow = eP + ((size_t)(b * NN + i) * DEE + cA) * NN;
      float uc = uu[cA];
      float acc = 0.f;
#pragma unroll
      for (int t = 0; t < 8; ++t) {
        int j0 = 4 * sA + 16 * t;
        float4 p = *(const float4*)&Prow[j0];
        float m0 = fmaxf(uc + G[j0 + 0][cA] + p.x, 0.f);
        float m1 = fmaxf(uc + G[j0 + 1][cA] + p.y, 0.f);
        float m2 = fmaxf(uc + G[j0 + 2][cA] + p.z, 0.f);
        float m3 = fmaxf(uc + G[j0 + 3][cA] + p.w, 0.f);
        acc += adjrow[j0] * m0 + adjrow[j0 + 1] * m1 + adjrow[j0 + 2] * m2 + adjrow[j0 + 3] * m3;
        if (WRITE_E) { float4 mm; mm.x = m0; mm.y = m1; mm.z = m2; mm.w = m3; *(float4*)&Prow[j0] = mm; }
      }
      acc += __shfl_down(acc, 1);
      acc += __shfl_down(acc, 2);
      if (sA == 0) ms[cA] = acc;
    }
    __syncthreads();

    // ---- Phase B: gates gi = W_ih @ m_sum + b_ih; GRU combine ----
    const float* GHrow = GH + ((size_t)b * NN + i) * 1536;
    float a1, a2 = 0.f;
    if (tid < 512) {
      a1 = b_ih[tid]; a2 = b_ih[1024 + tid];
      for (int c = 0; c < DEE; ++c) {
        float mv = ms[c];
        a1 += w_ihT[(size_t)c * 1536 + tid] * mv;
        a2 += w_ihT[(size_t)c * 1536 + 1024 + tid] * mv;
      }
    } else {
      a1 = b_ih[tid];
      for (int c = 0; c < DEE; ++c) a1 += w_ihT[(size_t)c * 1536 + tid] * ms[c];
    }
    if (tid >= 512) zb[tid - 512] = sigmf(a1 + GHrow[tid]);   // z gate
    __syncthreads();
    if (tid < 512) {
      float r = sigmf(a1 + GHrow[tid]);                       // r gate
      float nv = tanhf(a2 + r * GHrow[1024 + tid]);           // n gate
      float z = zb[tid];
      float hnew = (1.f - z) * nv + z * hv[tid];
      hn[tid] = hnew;
      h[((size_t)b * NN + i) * DVV + tid] = hnew;
    }
    __syncthreads();

    // ---- Phase C: G[:, i] = W2 @ h_new ----
    {
      float acc = 0.f;
      for (int t = 0; t < 128; ++t) {
        int d = sA + 4 * t;
        acc += w2T[(size_t)d * 256 + cA] * hn[d];
      }
      acc += __shfl_down(acc, 1);
      acc += __shfl_down(acc, 2);
      if (sA == 0) G[i][cA] = acc;
    }
    // next loop-top __syncthreads orders phase C before next phase A
  }
}

// ---------------- labels[b][n][c] = w_ro @ h_row + b_ro ----------------
__global__ __launch_bounds__(128) void k_labels(const float* __restrict__ h, const float* __restrict__ w_ro,
                                                const float* __restrict__ b_ro, float* __restrict__ out) {
  int b = blockIdx.x >> 7, n = blockIdx.x & 127;
  __shared__ __align__(16) float hr[512];
  int tid = threadIdx.x;
  *(float4*)&hr[tid * 4] = *(const float4*)&h[(size_t)((b << 7) + n) * DVV + tid * 4];
  __syncthreads();
  if (tid < NCC) {
    const float* w = w_ro + (size_t)tid * DVV;
    float acc = b_ro[tid];
    for (int d = 0; d < DVV; d += 4) {
      float4 wv = *(const float4*)&w[d];
      acc += wv.x * hr[d] + wv.y * hr[d + 1] + wv.z * hr[d + 2] + wv.w * hr[d + 3];
    }
    out[(size_t)((b << 7) + n) * NCC + tid] = acc;
  }
}

extern "C" void kernel_launch(void* const* d_in, const int* in_sizes, int n_in,
                              void* d_out, int out_size, void* d_ws, size_t ws_size,
                              hipStream_t stream) {
  const float* edge   = (const float*)d_in[0];
  const float* node   = (const float*)d_in[1];
  const float* w_link = (const float*)d_in[6];
  const float* b_link = (const float*)d_in[7];
  const float* w_msg  = (const float*)d_in[8];
  const float* b_msg  = (const float*)d_in[9];
  const float* w_ih   = (const float*)d_in[10];
  const float* w_hh   = (const float*)d_in[11];
  const float* b_ih   = (const float*)d_in[12];
  const float* b_hh   = (const float*)d_in[13];
  const float* w_ro   = (const float*)d_in[14];
  const float* b_ro   = (const float*)d_in[15];
  float* out = (float*)d_out;
  float* ws  = (float*)d_ws;

  // workspace layout (floats)
  float* e_buf  = ws;                      // 33,554,432  (B,N,DE,N) holds e / P in-place
  float* h_buf  = e_buf + 33554432ull;     //    524,288  (B,N,DV)
  float* GH_buf = h_buf + 524288;          //  1,572,864  (B,N,1536)
  float* U_buf  = GH_buf + 1572864;        //    262,144  (B,N,256)
  float* G_buf  = U_buf + 262144;          //    262,144  (B,N,256)
  float* lE_buf = G_buf + 262144;          //    131,072  (B,N,N)
  float* av_buf = lE_buf + 131072;         //      2,048  (B,2,N)
  float* w_ihT  = av_buf + 2048;           //    393,216  (256,1536)
  float* w2T    = w_ihT + 393216;          //    131,072  (512,256)
  size_t need_bytes = (36833280ull) * 4ull;
  if (ws_size < need_bytes) return;        // workspace too small: fail visibly

  // h init + weight transposes
  k_copy<<<512, 256, 0, stream>>>(node, h_buf);
  k_tr<<<(1536 * 256 + 255) / 256, 256, 0, stream>>>(w_ih, w_ihT, 1536, 256, 256, 0);
  k_tr<<<(256 * 512 + 255) / 256, 256, 0, stream>>>(w_msg, w2T, 256, 512, 1280, 512);

  for (int k = 0; k < 3; ++k) {
    k_av<<<1024, 128, 0, stream>>>(h_buf, w_link, av_buf);
    if (k == 0) k_plogit<1><<<1024, 256, 0, stream>>>(edge, w_msg, w_link, e_buf, lE_buf);
    else        k_plogit<0><<<1024, 256, 0, stream>>>(e_buf, w_msg, w_link, e_buf, lE_buf);
    k_adj<<<512, 256, 0, stream>>>(av_buf, lE_buf, b_link, out);
    k_wh<<<dim3(96, 8), 256, 0, stream>>>(w_hh, 512, 1536, b_hh, h_buf, GH_buf);
    k_wh<<<dim3(16, 8), 256, 0, stream>>>(w_msg, 1280, 256, b_msg, h_buf, U_buf);
    k_wh<<<dim3(16, 8), 256, 0, stream>>>(w_msg + 512, 1280, 256, nullptr, h_buf, G_buf);
    if (k < 2) k_scan<1><<<8, 1024, 0, stream>>>(e_buf, out, GH_buf, U_buf, G_buf, h_buf, w_ihT, b_ih, w2T);
    else       k_scan<0><<<8, 1024, 0, stream>>>(e_buf, out, GH_buf, U_buf, G_buf, h_buf, w_ihT, b_ih, w2T);
  }
  k_labels<<<1024, 128, 0, stream>>>(h_buf, w_ro, b_ro, out + 131072);
}

// Round 2
// 8427.656 us; speedup vs baseline: 1.5548x; 1.5548x over previous
//
#include <hip/hip_runtime.h>
#include <math.h>

// GPNN: B=8 graphs, N=128 nodes, DV=512, DE=256, K=3, C=117.
// R2: distributed scan — 16 blocks per batch, weights LDS-resident,
// 2 device-scope syncs per step.

#define NB 8
#define NN 128
#define DVV 512
#define DEE 256
#define NCC 117
#define SB 16          // blocks per batch in scan
#define RSL 96         // gate rows per block (1536/16)

__device__ __forceinline__ float sigmf(float x) {
  x = fminf(fmaxf(x, -30.f), 30.f);
  return 1.0f / (1.0f + __expf(-x));
}
__device__ __forceinline__ float tanhf_fast(float x) {
  x = fminf(fmaxf(x, -15.f), 15.f);
  float e = __expf(2.0f * x);
  return (e - 1.0f) / (e + 1.0f);
}

// ---------------- h init ----------------
__global__ __launch_bounds__(256) void k_copy(const float* __restrict__ src, float* __restrict__ dst) {
  int i = blockIdx.x * 256 + threadIdx.x;
  ((float4*)dst)[i] = ((const float4*)src)[i];
}

// ---------------- ai/aj ----------------
__global__ __launch_bounds__(128) void k_av(const float* __restrict__ h, const float* __restrict__ w_link,
                                            float* __restrict__ av) {
  int b = blockIdx.x >> 7, n = blockIdx.x & 127;
  int lane = threadIdx.x & 63, half = threadIdx.x >> 6;
  const float* hc = h + (size_t)((b << 7) + n) * DVV;
  const float* w = w_link + half * DVV;
  float acc = 0.f;
#pragma unroll
  for (int t = 0; t < 8; ++t) { int d = lane + (t << 6); acc += w[d] * hc[d]; }
#pragma unroll
  for (int off = 32; off; off >>= 1) acc += __shfl_down(acc, off);
  if (lane == 0) av[(b << 8) + half * NN + n] = acc;
}

// ---------------- per-row: logitE + P = W3 @ e_row (in place) ----------------
template <int FIRST>
__global__ __launch_bounds__(256) void k_plogit(const float* src, const float* __restrict__ w_msg,
                                                const float* __restrict__ w_link, float* e_buf,
                                                float* __restrict__ lE) {
  int b = blockIdx.x >> 7, i = blockIdx.x & 127;
  __shared__ __align__(16) float eL[DEE][132];
  int tid = threadIdx.x;
  if (FIRST) {
    const float* s0 = src + (size_t)(b * NN + i) * NN * DEE;
    for (int l = tid * 4; l < NN * DEE; l += 1024) {
      float4 v = *(const float4*)&s0[l];
      int c = l & 255, j = l >> 8;
      eL[c + 0][j] = v.x; eL[c + 1][j] = v.y; eL[c + 2][j] = v.z; eL[c + 3][j] = v.w;
    }
  } else {
    const float* s0 = src + (size_t)(b * NN + i) * DEE * NN;
    for (int l = tid * 4; l < NN * DEE; l += 1024) {
      int c = l >> 7, j = l & 127;
      *(float4*)&eL[c][j] = *(const float4*)&s0[l];
    }
  }
  __syncthreads();
  if (tid < NN) {
    float acc = 0.f;
    for (int c = 0; c < DEE; ++c) acc += w_link[1024 + c] * eL[c][tid];
    lE[((size_t)b * NN + i) * NN + tid] = acc;
  }
  int cg = tid >> 3, s = tid & 7;
  int c0 = cg * 8, jb = s * 16;
  float acc[8][16];
#pragma unroll
  for (int r = 0; r < 8; ++r)
#pragma unroll
    for (int u = 0; u < 16; ++u) acc[r][u] = 0.f;
  for (int c = 0; c < DEE; c += 4) {
    float4 w[8];
#pragma unroll
    for (int r = 0; r < 8; ++r) w[r] = *(const float4*)&w_msg[(size_t)(c0 + r) * 1280 + 1024 + c];
#pragma unroll
    for (int cc = 0; cc < 4; ++cc) {
      float4 e0 = *(const float4*)&eL[c + cc][jb];
      float4 e1 = *(const float4*)&eL[c + cc][jb + 4];
      float4 e2 = *(const float4*)&eL[c + cc][jb + 8];
      float4 e3 = *(const float4*)&eL[c + cc][jb + 12];
#pragma unroll
      for (int r = 0; r < 8; ++r) {
        float wv = ((const float*)&w[r])[cc];
        acc[r][0] += wv * e0.x;  acc[r][1] += wv * e0.y;  acc[r][2] += wv * e0.z;  acc[r][3] += wv * e0.w;
        acc[r][4] += wv * e1.x;  acc[r][5] += wv * e1.y;  acc[r][6] += wv * e1.z;  acc[r][7] += wv * e1.w;
        acc[r][8] += wv * e2.x;  acc[r][9] += wv * e2.y;  acc[r][10] += wv * e2.z; acc[r][11] += wv * e2.w;
        acc[r][12] += wv * e3.x; acc[r][13] += wv * e3.y; acc[r][14] += wv * e3.z; acc[r][15] += wv * e3.w;
      }
    }
  }
#pragma unroll
  for (int r = 0; r < 8; ++r)
#pragma unroll
    for (int u4 = 0; u4 < 4; ++u4) {
      float4 o; o.x = acc[r][u4 * 4]; o.y = acc[r][u4 * 4 + 1]; o.z = acc[r][u4 * 4 + 2]; o.w = acc[r][u4 * 4 + 3];
      *(float4*)&e_buf[((size_t)(b * NN + i) * DEE + c0 + r) * NN + jb + u4 * 4] = o;
    }
}

// ---------------- adj ----------------
__global__ __launch_bounds__(256) void k_adj(const float* __restrict__ av, const float* __restrict__ lE,
                                             const float* __restrict__ b_link, float* __restrict__ out) {
  int idx = blockIdx.x * 256 + threadIdx.x;
  int b = idx >> 14, r = idx & 16383, i = r >> 7, j = r & 127;
  float x = av[(b << 8) + NN + i] + av[(b << 8) + j] + lE[idx] + b_link[0];
  out[idx] = sigmf(x);
}

// ---------------- generic out[b][n][R] = W(R x 512) @ h_col(n) (+bias) ----------------
__global__ __launch_bounds__(256) void k_wh(const float* __restrict__ W, int ldw, int R,
                                            const float* bias, const float* __restrict__ h,
                                            float* __restrict__ out) {
  int r0 = blockIdx.x * 16, b = blockIdx.y;
  __shared__ float hT[128][129];
  __shared__ float wT[16][129];
  __shared__ float outT[16][129];
  int tid = threadIdx.x;
  int n = tid & 127, rr = tid >> 7;
  float acc8[8] = {0, 0, 0, 0, 0, 0, 0, 0};
  for (int dc = 0; dc < DVV; dc += 128) {
    if (dc) __syncthreads();
    for (int l = tid * 4; l < 16384; l += 1024) {
      int nn = l >> 7, d = l & 127;
      float4 v = *(const float4*)&h[((size_t)(b << 7) + nn) * DVV + dc + d];
      hT[d + 0][nn] = v.x; hT[d + 1][nn] = v.y; hT[d + 2][nn] = v.z; hT[d + 3][nn] = v.w;
    }
    for (int l = tid; l < 2048; l += 256) {
      int r = l >> 7, d = l & 127;
      wT[r][d] = W[(size_t)(r0 + r) * ldw + dc + d];
    }
    __syncthreads();
    for (int d = 0; d < 128; ++d) {
      float hval = hT[d][n];
#pragma unroll
      for (int r8 = 0; r8 < 8; ++r8) acc8[r8] += wT[rr * 8 + r8][d] * hval;
    }
  }
#pragma unroll
  for (int r8 = 0; r8 < 8; ++r8) {
    int r = rr * 8 + r8;
    outT[r][n] = acc8[r8] + (bias ? bias[r0 + r] : 0.0f);
  }
  __syncthreads();
  int n2 = tid >> 1, q = tid & 1;
  size_t base = ((size_t)(b << 7) + n2) * R + r0 + q * 8;
  float4 o0; o0.x = outT[q * 8 + 0][n2]; o0.y = outT[q * 8 + 1][n2]; o0.z = outT[q * 8 + 2][n2]; o0.w = outT[q * 8 + 3][n2];
  float4 o1; o1.x = outT[q * 8 + 4][n2]; o1.y = outT[q * 8 + 5][n2]; o1.z = outT[q * 8 + 6][n2]; o1.w = outT[q * 8 + 7][n2];
  *(float4*)&out[base] = o0;
  *(float4*)&out[base + 4] = o1;
}

// ---------------- distributed scan: 16 blocks per batch ----------------
// Block (s, b): owns c-slice [16s,16s+16) of messages/G, r-slice [96s,96s+96) of gates.
// LDS-resident: w_ih r-slice (98KB), W2 c-slice (33KB), G c-slice (8.7KB).
// Per step: A (m, msum slice) -> sync -> B (gi slice) -> sync -> GRU (replicated) + C (G col slice).
template <int WRITE_E>
__global__ __launch_bounds__(256) void k_scan2(
    float* eP, const float* __restrict__ adj, const float* __restrict__ GH,
    const float* __restrict__ U, const float* __restrict__ Gini, float* __restrict__ h,
    const float* __restrict__ w_ih, const float* __restrict__ b_ih,
    const float* __restrict__ w_msg, float* __restrict__ msum_g, float* __restrict__ gi_g,
    unsigned* cnt, int kround) {
  int s = blockIdx.x, b = blockIdx.y, tid = threadIdx.x;
  __shared__ float wihL[RSL * 257];    // [r_loc][c], pad 257 -> 2-way max
  __shared__ __align__(16) float w2L[16 * 520];  // [c_loc][d]
  __shared__ float GL[NN * 17];        // [j][c_loc]
  __shared__ __align__(16) float hvL[DVV];
  __shared__ float hnL[DVV];
  __shared__ float msL[DEE];
  __shared__ float adjL[NN];
  __shared__ float uuL[16];
  __shared__ float biL[RSL];
  unsigned* myc = cnt + b * 32;

  // prologue: weights -> LDS (coalesced global reads)
  {
    const float* wsrc = w_ih + (size_t)RSL * s * 256;
    for (int l = tid; l < RSL * 256; l += 256) {
      int r = l >> 8, c = l & 255;
      wihL[r * 257 + c] = wsrc[l];
    }
    for (int l = tid; l < 16 * 128; l += 256) {       // float4 granularity
      int c = l >> 7, d4 = (l & 127) * 4;
      *(float4*)&w2L[c * 520 + d4] = *(const float4*)&w_msg[(size_t)(16 * s + c) * 1280 + 512 + d4];
    }
    for (int l = tid; l < NN * 16; l += 256) {
      int j = l >> 4, c = l & 15;
      GL[j * 17 + c] = Gini[((size_t)b * NN + j) * DEE + 16 * s + c];
    }
    if (tid < RSL) biL[tid] = b_ih[RSL * s + tid];
  }

  const int wv = tid >> 6, lane = tid & 63;

  for (int i = 0; i < NN; ++i) {
    // preload step vectors
    if (tid < 128) adjL[tid] = adj[((size_t)b * NN + i) * NN + tid];
    if (tid < 16) uuL[tid] = U[((size_t)b * NN + i) * DEE + 16 * s + tid];
    if (tid >= 128) {
      int t4 = (tid - 128) * 4;
      *(float4*)&hvL[t4] = *(const float4*)&h[((size_t)b * NN + i) * DVV + t4];
    }
    __syncthreads();   // also orders prologue / prev phase C

    // ---- Phase A: c-slice of m, msum ----
    {
      float* Prow0 = eP + (((size_t)b * NN + i) * DEE + 16 * s) * NN;
      float msv[4];
#pragma unroll
      for (int cc = 0; cc < 4; ++cc) {
        int c = wv * 4 + cc;
        float uc = uuL[c];
        float* Pr = Prow0 + (size_t)c * NN;
        float acc = 0.f;
#pragma unroll
        for (int jh = 0; jh < 2; ++jh) {
          int j = lane + 64 * jh;
          float m = fmaxf(uc + GL[j * 17 + c] + Pr[j], 0.f);
          if (WRITE_E) Pr[j] = m;
          acc += adjL[j] * m;
        }
#pragma unroll
        for (int off = 32; off; off >>= 1) acc += __shfl_down(acc, off);
        msv[cc] = acc;
      }
      if (lane == 0) {
#pragma unroll
        for (int cc = 0; cc < 4; ++cc)
          msum_g[b * DEE + 16 * s + wv * 4 + cc] = msv[cc];
      }
    }
    // sync 1
    {
      unsigned target = SB * (unsigned)((kround * NN + i) * 2 + 1);
      __syncthreads();
      if (tid == 0) {
        __hip_atomic_fetch_add(myc, 1u, __ATOMIC_RELEASE, __HIP_MEMORY_SCOPE_AGENT);
        while (__hip_atomic_load(myc, __ATOMIC_ACQUIRE, __HIP_MEMORY_SCOPE_AGENT) < target)
          __builtin_amdgcn_s_sleep(1);
      }
      __syncthreads();
      __builtin_amdgcn_fence(__ATOMIC_ACQUIRE, "agent");
    }
    // ---- Phase B: gi r-slice from LDS w_ih ----
    msL[tid] = msum_g[b * DEE + tid];
    __syncthreads();
    {
      int r_loc = tid >> 1, hh = tid & 1;
      if (r_loc < RSL) {
        const float* wr = &wihL[r_loc * 257 + 128 * hh];
        const float* mp = &msL[128 * hh];
        float acc = 0.f;
#pragma unroll 8
        for (int c = 0; c < 128; ++c) acc += wr[c] * mp[c];
        acc += __shfl_down(acc, 1);
        if (hh == 0) gi_g[(size_t)b * 1536 + RSL * s + r_loc] = acc + biL[r_loc];
      }
    }
    // sync 2
    {
      unsigned target = SB * (unsigned)((kround * NN + i) * 2 + 2);
      __syncthreads();
      if (tid == 0) {
        __hip_atomic_fetch_add(myc, 1u, __ATOMIC_RELEASE, __HIP_MEMORY_SCOPE_AGENT);
        while (__hip_atomic_load(myc, __ATOMIC_ACQUIRE, __HIP_MEMORY_SCOPE_AGENT) < target)
          __builtin_amdgcn_s_sleep(1);
      }
      __syncthreads();
      __builtin_amdgcn_fence(__ATOMIC_ACQUIRE, "agent");
    }
    // ---- GRU (replicated; owner writes its h d-slice) ----
    {
      const float* GHrow = GH + ((size_t)b * NN + i) * 1536;
      const float* gir = gi_g + (size_t)b * 1536;
#pragma unroll
      for (int dh = 0; dh < 2; ++dh) {
        int d = tid + 256 * dh;
        float rg = sigmf(gir[d] + GHrow[d]);
        float z  = sigmf(gir[512 + d] + GHrow[512 + d]);
        float nv = tanhf_fast(gir[1024 + d] + rg * GHrow[1024 + d]);
        float hnew = (1.f - z) * nv + z * hvL[d];
        hnL[d] = hnew;
        if ((d >> 5) == s) h[((size_t)b * NN + i) * DVV + d] = hnew;
      }
    }
    __syncthreads();
    // ---- Phase C: G[i][c-slice] = W2slice @ h_new (local) ----
    {
      int c_loc = tid >> 4, dg = tid & 15;
      float acc = 0.f;
#pragma unroll 8
      for (int it = 0; it < 32; ++it) {
        int d = dg + 16 * it;
        acc += w2L[c_loc * 520 + d] * hnL[d];
      }
#pragma unroll
      for (int off = 8; off; off >>= 1) acc += __shfl_down(acc, off);
      if (dg == 0) GL[i * 17 + c_loc] = acc;
    }
    // loop-top __syncthreads orders C before next A
  }
}

// ---------------- labels ----------------
__global__ __launch_bounds__(128) void k_labels(const float* __restrict__ h, const float* __restrict__ w_ro,
                                                const float* __restrict__ b_ro, float* __restrict__ out) {
  int b = blockIdx.x >> 7, n = blockIdx.x & 127;
  __shared__ __align__(16) float hr[512];
  int tid = threadIdx.x;
  *(float4*)&hr[tid * 4] = *(const float4*)&h[(size_t)((b << 7) + n) * DVV + tid * 4];
  __syncthreads();
  if (tid < NCC) {
    const float* w = w_ro + (size_t)tid * DVV;
    float acc = b_ro[tid];
    for (int d = 0; d < DVV; d += 4) {
      float4 wv = *(const float4*)&w[d];
      acc += wv.x * hr[d] + wv.y * hr[d + 1] + wv.z * hr[d + 2] + wv.w * hr[d + 3];
    }
    out[(size_t)((b << 7) + n) * NCC + tid] = acc;
  }
}

extern "C" void kernel_launch(void* const* d_in, const int* in_sizes, int n_in,
                              void* d_out, int out_size, void* d_ws, size_t ws_size,
                              hipStream_t stream) {
  const float* edge   = (const float*)d_in[0];
  const float* node   = (const float*)d_in[1];
  const float* w_link = (const float*)d_in[6];
  const float* b_link = (const float*)d_in[7];
  const float* w_msg  = (const float*)d_in[8];
  const float* b_msg  = (const float*)d_in[9];
  const float* w_ih   = (const float*)d_in[10];
  const float* w_hh   = (const float*)d_in[11];
  const float* b_ih   = (const float*)d_in[12];
  const float* b_hh   = (const float*)d_in[13];
  const float* w_ro   = (const float*)d_in[14];
  const float* b_ro   = (const float*)d_in[15];
  float* out = (float*)d_out;
  float* ws  = (float*)d_ws;

  // workspace layout (floats)
  float* e_buf  = ws;                      // 33,554,432  (B,N,DE,N)
  float* h_buf  = e_buf + 33554432ull;     //    524,288  (B,N,DV)
  float* GH_buf = h_buf + 524288;          //  1,572,864  (B,N,1536)
  float* U_buf  = GH_buf + 1572864;        //    262,144  (B,N,256)
  float* G_buf  = U_buf + 262144;          //    262,144  (B,N,256)
  float* lE_buf = G_buf + 262144;          //    131,072  (B,N,N)
  float* av_buf = lE_buf + 131072;         //      2,048  (B,2,N)
  float* msum_g = av_buf + 2048;           //      2,048  (B,256)
  float* gi_g   = msum_g + 2048;           //     12,288  (B,1536)
  unsigned* cnt = (unsigned*)(gi_g + 12288);   //  256 u32 (B x 32 stride)
  size_t need_bytes = (36321536ull + 256ull) * 4ull;
  if (ws_size < need_bytes) return;

  hipMemsetAsync(cnt, 0, 256 * sizeof(unsigned), stream);
  k_copy<<<512, 256, 0, stream>>>(node, h_buf);

  for (int k = 0; k < 3; ++k) {
    k_av<<<1024, 128, 0, stream>>>(h_buf, w_link, av_buf);
    if (k == 0) k_plogit<1><<<1024, 256, 0, stream>>>(edge, w_msg, w_link, e_buf, lE_buf);
    else        k_plogit<0><<<1024, 256, 0, stream>>>(e_buf, w_msg, w_link, e_buf, lE_buf);
    k_adj<<<512, 256, 0, stream>>>(av_buf, lE_buf, b_link, out);
    k_wh<<<dim3(96, 8), 256, 0, stream>>>(w_hh, 512, 1536, b_hh, h_buf, GH_buf);
    k_wh<<<dim3(16, 8), 256, 0, stream>>>(w_msg, 1280, 256, b_msg, h_buf, U_buf);
    k_wh<<<dim3(16, 8), 256, 0, stream>>>(w_msg + 512, 1280, 256, nullptr, h_buf, G_buf);
    if (k < 2) k_scan2<1><<<dim3(SB, NB), 256, 0, stream>>>(e_buf, out, GH_buf, U_buf, G_buf, h_buf,
                                                            w_ih, b_ih, w_msg, msum_g, gi_g, cnt, k);
    else       k_scan2<0><<<dim3(SB, NB), 256, 0, stream>>>(e_buf, out, GH_buf, U_buf, G_buf, h_buf,
                                                            w_ih, b_ih, w_msg, msum_g, gi_g, cnt, k);
  }
  k_labels<<<1024, 128, 0, stream>>>(h_buf, w_ro, b_ro, out + 131072);
}

// Round 4
// 7977.029 us; speedup vs baseline: 1.6426x; 1.0565x over previous
//
#include <hip/hip_runtime.h>
#include <math.h>

// GPNN: B=8 graphs, N=128 nodes, DV=512, DE=256, K=3, C=117.
// R4: R3 structure (1 global sync/step, flag-array barrier, register prefetch)
// + double-buffered pg partial-gi exchange (fixes the R3 overwrite race).

#define NB 8
#define NN 128
#define DVV 512
#define DEE 256
#define NCC 117
#define SB 16          // blocks per batch in scan
#define PGOFF 196608   // floats per pg parity buffer (8*16*1536)

__device__ __forceinline__ float sigmf(float x) {
  x = fminf(fmaxf(x, -30.f), 30.f);
  return 1.0f / (1.0f + __expf(-x));
}
__device__ __forceinline__ float tanhf_fast(float x) {
  x = fminf(fmaxf(x, -15.f), 15.f);
  float e = __expf(2.0f * x);
  return (e - 1.0f) / (e + 1.0f);
}

// ---------------- h init ----------------
__global__ __launch_bounds__(256) void k_copy(const float* __restrict__ src, float* __restrict__ dst) {
  int i = blockIdx.x * 256 + threadIdx.x;
  ((float4*)dst)[i] = ((const float4*)src)[i];
}

// ---------------- ai/aj ----------------
__global__ __launch_bounds__(128) void k_av(const float* __restrict__ h, const float* __restrict__ w_link,
                                            float* __restrict__ av) {
  int b = blockIdx.x >> 7, n = blockIdx.x & 127;
  int lane = threadIdx.x & 63, half = threadIdx.x >> 6;
  const float* hc = h + (size_t)((b << 7) + n) * DVV;
  const float* w = w_link + half * DVV;
  float acc = 0.f;
#pragma unroll
  for (int t = 0; t < 8; ++t) { int d = lane + (t << 6); acc += w[d] * hc[d]; }
#pragma unroll
  for (int off = 32; off; off >>= 1) acc += __shfl_down(acc, off);
  if (lane == 0) av[(b << 8) + half * NN + n] = acc;
}

// ---------------- per-row: logitE + P = W3 @ e_row (in place) ----------------
template <int FIRST>
__global__ __launch_bounds__(256) void k_plogit(const float* src, const float* __restrict__ w_msg,
                                                const float* __restrict__ w_link, float* e_buf,
                                                float* __restrict__ lE) {
  int b = blockIdx.x >> 7, i = blockIdx.x & 127;
  __shared__ __align__(16) float eL[DEE][132];
  int tid = threadIdx.x;
  if (FIRST) {
    const float* s0 = src + (size_t)(b * NN + i) * NN * DEE;
    for (int l = tid * 4; l < NN * DEE; l += 1024) {
      float4 v = *(const float4*)&s0[l];
      int c = l & 255, j = l >> 8;
      eL[c + 0][j] = v.x; eL[c + 1][j] = v.y; eL[c + 2][j] = v.z; eL[c + 3][j] = v.w;
    }
  } else {
    const float* s0 = src + (size_t)(b * NN + i) * DEE * NN;
    for (int l = tid * 4; l < NN * DEE; l += 1024) {
      int c = l >> 7, j = l & 127;
      *(float4*)&eL[c][j] = *(const float4*)&s0[l];
    }
  }
  __syncthreads();
  if (tid < NN) {
    float acc = 0.f;
    for (int c = 0; c < DEE; ++c) acc += w_link[1024 + c] * eL[c][tid];
    lE[((size_t)b * NN + i) * NN + tid] = acc;
  }
  int cg = tid >> 3, s = tid & 7;
  int c0 = cg * 8, jb = s * 16;
  float acc[8][16];
#pragma unroll
  for (int r = 0; r < 8; ++r)
#pragma unroll
    for (int u = 0; u < 16; ++u) acc[r][u] = 0.f;
  for (int c = 0; c < DEE; c += 4) {
    float4 w[8];
#pragma unroll
    for (int r = 0; r < 8; ++r) w[r] = *(const float4*)&w_msg[(size_t)(c0 + r) * 1280 + 1024 + c];
#pragma unroll
    for (int cc = 0; cc < 4; ++cc) {
      float4 e0 = *(const float4*)&eL[c + cc][jb];
      float4 e1 = *(const float4*)&eL[c + cc][jb + 4];
      float4 e2 = *(const float4*)&eL[c + cc][jb + 8];
      float4 e3 = *(const float4*)&eL[c + cc][jb + 12];
#pragma unroll
      for (int r = 0; r < 8; ++r) {
        float wv = ((const float*)&w[r])[cc];
        acc[r][0] += wv * e0.x;  acc[r][1] += wv * e0.y;  acc[r][2] += wv * e0.z;  acc[r][3] += wv * e0.w;
        acc[r][4] += wv * e1.x;  acc[r][5] += wv * e1.y;  acc[r][6] += wv * e1.z;  acc[r][7] += wv * e1.w;
        acc[r][8] += wv * e2.x;  acc[r][9] += wv * e2.y;  acc[r][10] += wv * e2.z; acc[r][11] += wv * e2.w;
        acc[r][12] += wv * e3.x; acc[r][13] += wv * e3.y; acc[r][14] += wv * e3.z; acc[r][15] += wv * e3.w;
      }
    }
  }
#pragma unroll
  for (int r = 0; r < 8; ++r)
#pragma unroll
    for (int u4 = 0; u4 < 4; ++u4) {
      float4 o; o.x = acc[r][u4 * 4]; o.y = acc[r][u4 * 4 + 1]; o.z = acc[r][u4 * 4 + 2]; o.w = acc[r][u4 * 4 + 3];
      *(float4*)&e_buf[((size_t)(b * NN + i) * DEE + c0 + r) * NN + jb + u4 * 4] = o;
    }
}

// ---------------- adj ----------------
__global__ __launch_bounds__(256) void k_adj(const float* __restrict__ av, const float* __restrict__ lE,
                                             const float* __restrict__ b_link, float* __restrict__ out) {
  int idx = blockIdx.x * 256 + threadIdx.x;
  int b = idx >> 14, r = idx & 16383, i = r >> 7, j = r & 127;
  float x = av[(b << 8) + NN + i] + av[(b << 8) + j] + lE[idx] + b_link[0];
  out[idx] = sigmf(x);
}

// ---------------- generic out[b][n][R] = W(R x 512) @ h_col(n) (+bias) ----------------
__global__ __launch_bounds__(256) void k_wh(const float* __restrict__ W, int ldw, int R,
                                            const float* bias, const float* __restrict__ h,
                                            float* __restrict__ out) {
  int r0 = blockIdx.x * 16, b = blockIdx.y;
  __shared__ float hT[128][129];
  __shared__ float wT[16][129];
  __shared__ float outT[16][129];
  int tid = threadIdx.x;
  int n = tid & 127, rr = tid >> 7;
  float acc8[8] = {0, 0, 0, 0, 0, 0, 0, 0};
  for (int dc = 0; dc < DVV; dc += 128) {
    if (dc) __syncthreads();
    for (int l = tid * 4; l < 16384; l += 1024) {
      int nn = l >> 7, d = l & 127;
      float4 v = *(const float4*)&h[((size_t)(b << 7) + nn) * DVV + dc + d];
      hT[d + 0][nn] = v.x; hT[d + 1][nn] = v.y; hT[d + 2][nn] = v.z; hT[d + 3][nn] = v.w;
    }
    for (int l = tid; l < 2048; l += 256) {
      int r = l >> 7, d = l & 127;
      wT[r][d] = W[(size_t)(r0 + r) * ldw + dc + d];
    }
    __syncthreads();
    for (int d = 0; d < 128; ++d) {
      float hval = hT[d][n];
#pragma unroll
      for (int r8 = 0; r8 < 8; ++r8) acc8[r8] += wT[rr * 8 + r8][d] * hval;
    }
  }
#pragma unroll
  for (int r8 = 0; r8 < 8; ++r8) {
    int r = rr * 8 + r8;
    outT[r][n] = acc8[r8] + (bias ? bias[r0 + r] : 0.0f);
  }
  __syncthreads();
  int n2 = tid >> 1, q = tid & 1;
  size_t base = ((size_t)(b << 7) + n2) * R + r0 + q * 8;
  float4 o0; o0.x = outT[q * 8 + 0][n2]; o0.y = outT[q * 8 + 1][n2]; o0.z = outT[q * 8 + 2][n2]; o0.w = outT[q * 8 + 3][n2];
  float4 o1; o1.x = outT[q * 8 + 4][n2]; o1.y = outT[q * 8 + 5][n2]; o1.z = outT[q * 8 + 6][n2]; o1.w = outT[q * 8 + 7][n2];
  *(float4*)&out[base] = o0;
  *(float4*)&out[base + 4] = o1;
}

// ---------------- distributed scan: 16 blocks per batch, 1 sync/step ----------------
// Block (s,b): c-slice [16s,16s+16) of messages/G AND of W_ih columns.
// Per step: A (m, msum slice — local) ; B (partial gi -> pg[par][b][s][:])
//           -> ONE flag-barrier -> GRU (sum 16 partials + bias, replicated) ; C (G col, local).
// pg is double-buffered by step parity: writer of parity p at step i+2 can only
// run after barrier i+1, which all readers of parity p (step i GRU) precede.
template <int WRITE_E>
__global__ __launch_bounds__(256) void k_scan4(
    float* eP, const float* __restrict__ adj, const float* __restrict__ GH,
    const float* __restrict__ U, const float* __restrict__ Gini, float* __restrict__ h,
    const float* __restrict__ w_ih, const float* __restrict__ b_ih,
    const float* __restrict__ w_msg, float* __restrict__ pg,
    unsigned* __restrict__ flags, int kround) {
  const int s = blockIdx.x, b = blockIdx.y, tid = threadIdx.x;
  __shared__ float wihL[16 * 1540];              // [c_loc][r] pad -> ~98.6 KB
  __shared__ __align__(16) float w2L[16 * 520];  // [c_loc][d] 33.3 KB
  __shared__ __align__(16) float GL[16 * 132];   // [c_loc][j] 8.4 KB
  __shared__ float hnL[DVV];
  __shared__ float msL[16];

  // ---- prologue: weights -> LDS ----
  for (int l = tid; l < 1536 * 16; l += 256) {
    int r = l >> 4, c = l & 15;
    wihL[c * 1540 + r] = w_ih[(size_t)r * 256 + 16 * s + c];
  }
  for (int l = tid; l < 16 * 128; l += 256) {
    int c = l >> 7, d4 = (l & 127) * 4;
    *(float4*)&w2L[c * 520 + d4] = *(const float4*)&w_msg[(size_t)(16 * s + c) * 1280 + 512 + d4];
  }
  for (int l = tid; l < 2048; l += 256) {
    int c = l & 15, j = l >> 4;
    GL[c * 132 + j] = Gini[((size_t)b * NN + j) * DEE + 16 * s + c];
  }
  float bi0 = b_ih[tid], bi1 = b_ih[tid + 256];
  float bi2 = b_ih[512 + tid], bi3 = b_ih[768 + tid];
  float bi4 = b_ih[1024 + tid], bi5 = b_ih[1280 + tid];

  const int c_loc = tid >> 4, jg = tid & 15, j0 = jg << 3;

  // ---- prefetch step 0 ----
  float4 P0, P1, A0, A1; float uu;
  float hv0, hv1, ghr0, ghr1, ghz0, ghz1, ghn0, ghn1;
  {
    size_t rE = ((size_t)(b * NN + 0) * DEE + 16 * s + c_loc) * NN + j0;
    P0 = *(const float4*)&eP[rE]; P1 = *(const float4*)&eP[rE + 4];
    size_t rA = (size_t)(b * NN + 0) * NN + j0;
    A0 = *(const float4*)&adj[rA]; A1 = *(const float4*)&adj[rA + 4];
    uu = U[(size_t)(b * NN + 0) * DEE + 16 * s + c_loc];
    size_t rH = (size_t)(b * NN + 0) * DVV;
    hv0 = h[rH + tid]; hv1 = h[rH + tid + 256];
    size_t rG = (size_t)(b * NN + 0) * 1536;
    ghr0 = GH[rG + tid]; ghr1 = GH[rG + tid + 256];
    ghz0 = GH[rG + 512 + tid]; ghz1 = GH[rG + 768 + tid];
    ghn0 = GH[rG + 1024 + tid]; ghn1 = GH[rG + 1280 + tid];
  }

  for (int i = 0; i < NN; ++i) {
    float* pgb = pg + (size_t)(i & 1) * PGOFF + (size_t)((b << 4) + s) * 1536;
    const float* pgr = pg + (size_t)(i & 1) * PGOFF + (size_t)(b << 4) * 1536;
    __syncthreads();   // (1) GL col i-1 / prologue visible; hnL reusable

    // ---- Phase A: m for (c_loc, j0..j0+7), msum partial ----
    float acc;
    {
      const float* gl = &GL[c_loc * 132 + j0];
      float4 g0 = *(const float4*)&gl[0];
      float4 g1 = *(const float4*)&gl[4];
      float m0 = fmaxf(uu + g0.x + P0.x, 0.f), m1 = fmaxf(uu + g0.y + P0.y, 0.f);
      float m2 = fmaxf(uu + g0.z + P0.z, 0.f), m3 = fmaxf(uu + g0.w + P0.w, 0.f);
      float m4 = fmaxf(uu + g1.x + P1.x, 0.f), m5 = fmaxf(uu + g1.y + P1.y, 0.f);
      float m6 = fmaxf(uu + g1.z + P1.z, 0.f), m7 = fmaxf(uu + g1.w + P1.w, 0.f);
      acc = A0.x * m0 + A0.y * m1 + A0.z * m2 + A0.w * m3
          + A1.x * m4 + A1.y * m5 + A1.z * m6 + A1.w * m7;
      if (WRITE_E) {
        size_t rE = ((size_t)(b * NN + i) * DEE + 16 * s + c_loc) * NN + j0;
        float4 w0; w0.x = m0; w0.y = m1; w0.z = m2; w0.w = m3;
        float4 w1; w1.x = m4; w1.y = m5; w1.z = m6; w1.w = m7;
        *(float4*)&eP[rE] = w0; *(float4*)&eP[rE + 4] = w1;
      }
    }
    // prefetch P/adj/U for i+1 (clamped) — overlaps B + sync
    {
      int in = (i < NN - 1) ? i + 1 : NN - 1;
      size_t rE = ((size_t)(b * NN + in) * DEE + 16 * s + c_loc) * NN + j0;
      P0 = *(const float4*)&eP[rE]; P1 = *(const float4*)&eP[rE + 4];
      size_t rA = (size_t)(b * NN + in) * NN + j0;
      A0 = *(const float4*)&adj[rA]; A1 = *(const float4*)&adj[rA + 4];
      uu = U[(size_t)(b * NN + in) * DEE + 16 * s + c_loc];
    }
    // reduce msum within the 16-thread c-group
    acc += __shfl_down(acc, 8);
    acc += __shfl_down(acc, 4);
    acc += __shfl_down(acc, 2);
    acc += __shfl_down(acc, 1);
    if (jg == 0) msL[c_loc] = acc;
    __syncthreads();   // (2) msL ready

    // ---- Phase B: partial gi from own c-slice ----
    {
      float ms[16];
#pragma unroll
      for (int c = 0; c < 16; ++c) ms[c] = msL[c];
#pragma unroll
      for (int u = 0; u < 6; ++u) {
        int r = tid + (u << 8);
        float pa = 0.f;
#pragma unroll
        for (int c = 0; c < 16; ++c) pa += wihL[c * 1540 + r] * ms[c];
        pgb[r] = pa;
      }
    }

    // ---- ONE global sync: flag-array barrier ----
    {
      unsigned tgt = (unsigned)(kround * NN + i + 1);
      __syncthreads();   // (3) drains pg stores for every thread
      __builtin_amdgcn_fence(__ATOMIC_RELEASE, "agent");
      if (tid < 64) {
        if (tid == 0)
          __hip_atomic_store(&flags[(((b << 4) + s) << 5)], tgt, __ATOMIC_RELEASE,
                             __HIP_MEMORY_SCOPE_AGENT);
        const unsigned* fp = &flags[(((b << 4) + (tid & 15)) << 5)];
        for (;;) {
          unsigned v = __hip_atomic_load(fp, __ATOMIC_ACQUIRE, __HIP_MEMORY_SCOPE_AGENT);
          if (!__any(v < tgt)) break;
          __builtin_amdgcn_s_sleep(1);
        }
      }
      __syncthreads();   // (4)
      __builtin_amdgcn_fence(__ATOMIC_ACQUIRE, "agent");
    }

    // ---- GRU (replicated): sum 16 partials + bias ----
    {
      float sr0 = bi0, sr1 = bi1, sz0 = bi2, sz1 = bi3, sn0 = bi4, sn1 = bi5;
#pragma unroll
      for (int ss = 0; ss < 16; ++ss) {
        const float* p = pgr + (size_t)ss * 1536;
        sr0 += p[tid];        sr1 += p[tid + 256];
        sz0 += p[512 + tid];  sz1 += p[768 + tid];
        sn0 += p[1024 + tid]; sn1 += p[1280 + tid];
      }
      float rg0 = sigmf(sr0 + ghr0), rg1 = sigmf(sr1 + ghr1);
      float z0 = sigmf(sz0 + ghz0),  z1 = sigmf(sz1 + ghz1);
      float nv0 = tanhf_fast(sn0 + rg0 * ghn0);
      float nv1 = tanhf_fast(sn1 + rg1 * ghn1);
      float hn0 = (1.f - z0) * nv0 + z0 * hv0;
      float hn1 = (1.f - z1) * nv1 + z1 * hv1;
      hnL[tid] = hn0; hnL[tid + 256] = hn1;
      size_t rH = (size_t)(b * NN + i) * DVV;
      if ((tid >> 5) == s) h[rH + tid] = hn0;
      if (((tid + 256) >> 5) == s) h[rH + tid + 256] = hn1;
    }
    // prefetch hv/GH for i+1 (clamped) — overlaps C + next A
    {
      int in = (i < NN - 1) ? i + 1 : NN - 1;
      size_t rH = (size_t)(b * NN + in) * DVV;
      hv0 = h[rH + tid]; hv1 = h[rH + tid + 256];
      size_t rG = (size_t)(b * NN + in) * 1536;
      ghr0 = GH[rG + tid]; ghr1 = GH[rG + tid + 256];
      ghz0 = GH[rG + 512 + tid]; ghz1 = GH[rG + 768 + tid];
      ghn0 = GH[rG + 1024 + tid]; ghn1 = GH[rG + 1280 + tid];
    }
    __syncthreads();   // (5) hnL ready

    // ---- Phase C: G[c_loc-slice][i] = W2slice @ h_new ----
    {
      int cw = tid >> 4, dg = tid & 15;
      float acc2 = 0.f;
#pragma unroll
      for (int it = 0; it < 32; ++it) {
        int d = dg + (it << 4);
        acc2 += w2L[cw * 520 + d] * hnL[d];
      }
      acc2 += __shfl_down(acc2, 8);
      acc2 += __shfl_down(acc2, 4);
      acc2 += __shfl_down(acc2, 2);
      acc2 += __shfl_down(acc2, 1);
      if (dg == 0) GL[cw * 132 + i] = acc2;
    }
  }
}

// ---------------- labels ----------------
__global__ __launch_bounds__(128) void k_labels(const float* __restrict__ h, const float* __restrict__ w_ro,
                                                const float* __restrict__ b_ro, float* __restrict__ out) {
  int b = blockIdx.x >> 7, n = blockIdx.x & 127;
  __shared__ __align__(16) float hr[512];
  int tid = threadIdx.x;
  *(float4*)&hr[tid * 4] = *(const float4*)&h[(size_t)((b << 7) + n) * DVV + tid * 4];
  __syncthreads();
  if (tid < NCC) {
    const float* w = w_ro + (size_t)tid * DVV;
    float acc = b_ro[tid];
    for (int d = 0; d < DVV; d += 4) {
      float4 wv = *(const float4*)&w[d];
      acc += wv.x * hr[d] + wv.y * hr[d + 1] + wv.z * hr[d + 2] + wv.w * hr[d + 3];
    }
    out[(size_t)((b << 7) + n) * NCC + tid] = acc;
  }
}

extern "C" void kernel_launch(void* const* d_in, const int* in_sizes, int n_in,
                              void* d_out, int out_size, void* d_ws, size_t ws_size,
                              hipStream_t stream) {
  const float* edge   = (const float*)d_in[0];
  const float* node   = (const float*)d_in[1];
  const float* w_link = (const float*)d_in[6];
  const float* b_link = (const float*)d_in[7];
  const float* w_msg  = (const float*)d_in[8];
  const float* b_msg  = (const float*)d_in[9];
  const float* w_ih   = (const float*)d_in[10];
  const float* w_hh   = (const float*)d_in[11];
  const float* b_ih   = (const float*)d_in[12];
  const float* b_hh   = (const float*)d_in[13];
  const float* w_ro   = (const float*)d_in[14];
  const float* b_ro   = (const float*)d_in[15];
  float* out = (float*)d_out;
  float* ws  = (float*)d_ws;

  // workspace layout (floats)
  float* e_buf  = ws;                      // 33,554,432  (B,N,DE,N)
  float* h_buf  = e_buf + 33554432ull;     //    524,288  (B,N,DV)
  float* GH_buf = h_buf + 524288;          //  1,572,864  (B,N,1536)
  float* U_buf  = GH_buf + 1572864;        //    262,144  (B,N,256)
  float* G_buf  = U_buf + 262144;          //    262,144  (B,N,256)
  float* lE_buf = G_buf + 262144;          //    131,072  (B,N,N)
  float* av_buf = lE_buf + 131072;         //      2,048  (B,2,N)
  float* pg_buf = av_buf + 2048;           //    393,216  (2,B,16,1536) double-buffered
  unsigned* flags = (unsigned*)(pg_buf + 2 * PGOFF);  // 8*16*32 u32 = 4096
  size_t need_bytes = 36710304ull * 4ull;
  if (ws_size < need_bytes) return;

  hipMemsetAsync(flags, 0, 4096 * sizeof(unsigned), stream);
  k_copy<<<512, 256, 0, stream>>>(node, h_buf);

  for (int k = 0; k < 3; ++k) {
    k_av<<<1024, 128, 0, stream>>>(h_buf, w_link, av_buf);
    if (k == 0) k_plogit<1><<<1024, 256, 0, stream>>>(edge, w_msg, w_link, e_buf, lE_buf);
    else        k_plogit<0><<<1024, 256, 0, stream>>>(e_buf, w_msg, w_link, e_buf, lE_buf);
    k_adj<<<512, 256, 0, stream>>>(av_buf, lE_buf, b_link, out);
    k_wh<<<dim3(96, 8), 256, 0, stream>>>(w_hh, 512, 1536, b_hh, h_buf, GH_buf);
    k_wh<<<dim3(16, 8), 256, 0, stream>>>(w_msg, 1280, 256, b_msg, h_buf, U_buf);
    k_wh<<<dim3(16, 8), 256, 0, stream>>>(w_msg + 512, 1280, 256, nullptr, h_buf, G_buf);
    if (k < 2) k_scan4<1><<<dim3(SB, NB), 256, 0, stream>>>(e_buf, out, GH_buf, U_buf, G_buf, h_buf,
                                                            w_ih, b_ih, w_msg, pg_buf, flags, k);
    else       k_scan4<0><<<dim3(SB, NB), 256, 0, stream>>>(e_buf, out, GH_buf, U_buf, G_buf, h_buf,
                                                            w_ih, b_ih, w_msg, pg_buf, flags, k);
  }
  k_labels<<<1024, 128, 0, stream>>>(h_buf, w_ro, b_ro, out + 131072);
}

// Round 5
// 3061.632 us; speedup vs baseline: 4.2798x; 2.6055x over previous
//
#include <hip/hip_runtime.h>
#include <math.h>

// GPNN: B=8 graphs, N=128 nodes, DV=512, DE=256, K=3, C=117.
// R5: R4 structure, but NO agent fences (they compile to full L2 wb/inv = 457MB
// refetch). All cross-block exchange (pg, flags) via relaxed agent-scope atomics
// (sc1, L2-bypass, complete at coherent L3). Ordering via barrier vmcnt drains.

#define NB 8
#define NN 128
#define DVV 512
#define DEE 256
#define NCC 117
#define SB 16          // blocks per batch in scan
#define PGOFF 196608   // floats per pg parity buffer (8*16*1536)

__device__ __forceinline__ float sigmf(float x) {
  x = fminf(fmaxf(x, -30.f), 30.f);
  return 1.0f / (1.0f + __expf(-x));
}
__device__ __forceinline__ float tanhf_fast(float x) {
  x = fminf(fmaxf(x, -15.f), 15.f);
  float e = __expf(2.0f * x);
  return (e - 1.0f) / (e + 1.0f);
}

// ---------------- h init ----------------
__global__ __launch_bounds__(256) void k_copy(const float* __restrict__ src, float* __restrict__ dst) {
  int i = blockIdx.x * 256 + threadIdx.x;
  ((float4*)dst)[i] = ((const float4*)src)[i];
}

// ---------------- ai/aj ----------------
__global__ __launch_bounds__(128) void k_av(const float* __restrict__ h, const float* __restrict__ w_link,
                                            float* __restrict__ av) {
  int b = blockIdx.x >> 7, n = blockIdx.x & 127;
  int lane = threadIdx.x & 63, half = threadIdx.x >> 6;
  const float* hc = h + (size_t)((b << 7) + n) * DVV;
  const float* w = w_link + half * DVV;
  float acc = 0.f;
#pragma unroll
  for (int t = 0; t < 8; ++t) { int d = lane + (t << 6); acc += w[d] * hc[d]; }
#pragma unroll
  for (int off = 32; off; off >>= 1) acc += __shfl_down(acc, off);
  if (lane == 0) av[(b << 8) + half * NN + n] = acc;
}

// ---------------- per-row: logitE + P = W3 @ e_row (in place) ----------------
template <int FIRST>
__global__ __launch_bounds__(256) void k_plogit(const float* src, const float* __restrict__ w_msg,
                                                const float* __restrict__ w_link, float* e_buf,
                                                float* __restrict__ lE) {
  int b = blockIdx.x >> 7, i = blockIdx.x & 127;
  __shared__ __align__(16) float eL[DEE][132];
  int tid = threadIdx.x;
  if (FIRST) {
    const float* s0 = src + (size_t)(b * NN + i) * NN * DEE;
    for (int l = tid * 4; l < NN * DEE; l += 1024) {
      float4 v = *(const float4*)&s0[l];
      int c = l & 255, j = l >> 8;
      eL[c + 0][j] = v.x; eL[c + 1][j] = v.y; eL[c + 2][j] = v.z; eL[c + 3][j] = v.w;
    }
  } else {
    const float* s0 = src + (size_t)(b * NN + i) * DEE * NN;
    for (int l = tid * 4; l < NN * DEE; l += 1024) {
      int c = l >> 7, j = l & 127;
      *(float4*)&eL[c][j] = *(const float4*)&s0[l];
    }
  }
  __syncthreads();
  if (tid < NN) {
    float acc = 0.f;
    for (int c = 0; c < DEE; ++c) acc += w_link[1024 + c] * eL[c][tid];
    lE[((size_t)b * NN + i) * NN + tid] = acc;
  }
  int cg = tid >> 3, s = tid & 7;
  int c0 = cg * 8, jb = s * 16;
  float acc[8][16];
#pragma unroll
  for (int r = 0; r < 8; ++r)
#pragma unroll
    for (int u = 0; u < 16; ++u) acc[r][u] = 0.f;
  for (int c = 0; c < DEE; c += 4) {
    float4 w[8];
#pragma unroll
    for (int r = 0; r < 8; ++r) w[r] = *(const float4*)&w_msg[(size_t)(c0 + r) * 1280 + 1024 + c];
#pragma unroll
    for (int cc = 0; cc < 4; ++cc) {
      float4 e0 = *(const float4*)&eL[c + cc][jb];
      float4 e1 = *(const float4*)&eL[c + cc][jb + 4];
      float4 e2 = *(const float4*)&eL[c + cc][jb + 8];
      float4 e3 = *(const float4*)&eL[c + cc][jb + 12];
#pragma unroll
      for (int r = 0; r < 8; ++r) {
        float wv = ((const float*)&w[r])[cc];
        acc[r][0] += wv * e0.x;  acc[r][1] += wv * e0.y;  acc[r][2] += wv * e0.z;  acc[r][3] += wv * e0.w;
        acc[r][4] += wv * e1.x;  acc[r][5] += wv * e1.y;  acc[r][6] += wv * e1.z;  acc[r][7] += wv * e1.w;
        acc[r][8] += wv * e2.x;  acc[r][9] += wv * e2.y;  acc[r][10] += wv * e2.z; acc[r][11] += wv * e2.w;
        acc[r][12] += wv * e3.x; acc[r][13] += wv * e3.y; acc[r][14] += wv * e3.z; acc[r][15] += wv * e3.w;
      }
    }
  }
#pragma unroll
  for (int r = 0; r < 8; ++r)
#pragma unroll
    for (int u4 = 0; u4 < 4; ++u4) {
      float4 o; o.x = acc[r][u4 * 4]; o.y = acc[r][u4 * 4 + 1]; o.z = acc[r][u4 * 4 + 2]; o.w = acc[r][u4 * 4 + 3];
      *(float4*)&e_buf[((size_t)(b * NN + i) * DEE + c0 + r) * NN + jb + u4 * 4] = o;
    }
}

// ---------------- adj ----------------
__global__ __launch_bounds__(256) void k_adj(const float* __restrict__ av, const float* __restrict__ lE,
                                             const float* __restrict__ b_link, float* __restrict__ out) {
  int idx = blockIdx.x * 256 + threadIdx.x;
  int b = idx >> 14, r = idx & 16383, i = r >> 7, j = r & 127;
  float x = av[(b << 8) + NN + i] + av[(b << 8) + j] + lE[idx] + b_link[0];
  out[idx] = sigmf(x);
}

// ---------------- generic out[b][n][R] = W(R x 512) @ h_col(n) (+bias) ----------------
__global__ __launch_bounds__(256) void k_wh(const float* __restrict__ W, int ldw, int R,
                                            const float* bias, const float* __restrict__ h,
                                            float* __restrict__ out) {
  int r0 = blockIdx.x * 16, b = blockIdx.y;
  __shared__ float hT[128][129];
  __shared__ float wT[16][129];
  __shared__ float outT[16][129];
  int tid = threadIdx.x;
  int n = tid & 127, rr = tid >> 7;
  float acc8[8] = {0, 0, 0, 0, 0, 0, 0, 0};
  for (int dc = 0; dc < DVV; dc += 128) {
    if (dc) __syncthreads();
    for (int l = tid * 4; l < 16384; l += 1024) {
      int nn = l >> 7, d = l & 127;
      float4 v = *(const float4*)&h[((size_t)(b << 7) + nn) * DVV + dc + d];
      hT[d + 0][nn] = v.x; hT[d + 1][nn] = v.y; hT[d + 2][nn] = v.z; hT[d + 3][nn] = v.w;
    }
    for (int l = tid; l < 2048; l += 256) {
      int r = l >> 7, d = l & 127;
      wT[r][d] = W[(size_t)(r0 + r) * ldw + dc + d];
    }
    __syncthreads();
    for (int d = 0; d < 128; ++d) {
      float hval = hT[d][n];
#pragma unroll
      for (int r8 = 0; r8 < 8; ++r8) acc8[r8] += wT[rr * 8 + r8][d] * hval;
    }
  }
#pragma unroll
  for (int r8 = 0; r8 < 8; ++r8) {
    int r = rr * 8 + r8;
    outT[r][n] = acc8[r8] + (bias ? bias[r0 + r] : 0.0f);
  }
  __syncthreads();
  int n2 = tid >> 1, q = tid & 1;
  size_t base = ((size_t)(b << 7) + n2) * R + r0 + q * 8;
  float4 o0; o0.x = outT[q * 8 + 0][n2]; o0.y = outT[q * 8 + 1][n2]; o0.z = outT[q * 8 + 2][n2]; o0.w = outT[q * 8 + 3][n2];
  float4 o1; o1.x = outT[q * 8 + 4][n2]; o1.y = outT[q * 8 + 5][n2]; o1.z = outT[q * 8 + 6][n2]; o1.w = outT[q * 8 + 7][n2];
  *(float4*)&out[base] = o0;
  *(float4*)&out[base + 4] = o1;
}

// ---------------- distributed scan: 16 blocks per batch, 1 sync/step ----------------
// Exchange (pg double-buffered by parity, flags) via RELAXED agent-scope atomics:
// sc1 L2-bypass ops completing at the coherent L3 — no buffer_wbl2/buffer_inv.
// Ordering: compiler's s_waitcnt vmcnt(0) before each s_barrier drains the sc1
// stores; flag set after barrier => partials L3-visible to sc1 reader loads.
template <int WRITE_E>
__global__ __launch_bounds__(256) void k_scan5(
    float* eP, const float* __restrict__ adj, const float* __restrict__ GH,
    const float* __restrict__ U, const float* __restrict__ Gini, float* __restrict__ h,
    const float* __restrict__ w_ih, const float* __restrict__ b_ih,
    const float* __restrict__ w_msg, float* __restrict__ pg,
    unsigned* __restrict__ flags, int kround) {
  const int s = blockIdx.x, b = blockIdx.y, tid = threadIdx.x;
  __shared__ float wihL[16 * 1540];              // [c_loc][r] pad -> ~98.6 KB
  __shared__ __align__(16) float w2L[16 * 520];  // [c_loc][d] 33.3 KB
  __shared__ __align__(16) float GL[16 * 132];   // [c_loc][j] 8.4 KB
  __shared__ float hnL[DVV];
  __shared__ float msL[16];

  // ---- prologue: weights -> LDS ----
  for (int l = tid; l < 1536 * 16; l += 256) {
    int r = l >> 4, c = l & 15;
    wihL[c * 1540 + r] = w_ih[(size_t)r * 256 + 16 * s + c];
  }
  for (int l = tid; l < 16 * 128; l += 256) {
    int c = l >> 7, d4 = (l & 127) * 4;
    *(float4*)&w2L[c * 520 + d4] = *(const float4*)&w_msg[(size_t)(16 * s + c) * 1280 + 512 + d4];
  }
  for (int l = tid; l < 2048; l += 256) {
    int c = l & 15, j = l >> 4;
    GL[c * 132 + j] = Gini[((size_t)b * NN + j) * DEE + 16 * s + c];
  }
  float bi0 = b_ih[tid], bi1 = b_ih[tid + 256];
  float bi2 = b_ih[512 + tid], bi3 = b_ih[768 + tid];
  float bi4 = b_ih[1024 + tid], bi5 = b_ih[1280 + tid];

  const int c_loc = tid >> 4, jg = tid & 15, j0 = jg << 3;

  // ---- prefetch step 0 ----
  float4 P0, P1, A0, A1; float uu;
  float hv0, hv1, ghr0, ghr1, ghz0, ghz1, ghn0, ghn1;
  {
    size_t rE = ((size_t)(b * NN + 0) * DEE + 16 * s + c_loc) * NN + j0;
    P0 = *(const float4*)&eP[rE]; P1 = *(const float4*)&eP[rE + 4];
    size_t rA = (size_t)(b * NN + 0) * NN + j0;
    A0 = *(const float4*)&adj[rA]; A1 = *(const float4*)&adj[rA + 4];
    uu = U[(size_t)(b * NN + 0) * DEE + 16 * s + c_loc];
    size_t rH = (size_t)(b * NN + 0) * DVV;
    hv0 = h[rH + tid]; hv1 = h[rH + tid + 256];
    size_t rG = (size_t)(b * NN + 0) * 1536;
    ghr0 = GH[rG + tid]; ghr1 = GH[rG + tid + 256];
    ghz0 = GH[rG + 512 + tid]; ghz1 = GH[rG + 768 + tid];
    ghn0 = GH[rG + 1024 + tid]; ghn1 = GH[rG + 1280 + tid];
  }

  for (int i = 0; i < NN; ++i) {
    float* pgb = pg + (size_t)(i & 1) * PGOFF + (size_t)((b << 4) + s) * 1536;
    float* pgr = pg + (size_t)(i & 1) * PGOFF + (size_t)(b << 4) * 1536;
    __syncthreads();   // (1) GL col i-1 / prologue visible; hnL reusable

    // ---- Phase A: m for (c_loc, j0..j0+7), msum partial ----
    float acc;
    {
      const float* gl = &GL[c_loc * 132 + j0];
      float4 g0 = *(const float4*)&gl[0];
      float4 g1 = *(const float4*)&gl[4];
      float m0 = fmaxf(uu + g0.x + P0.x, 0.f), m1 = fmaxf(uu + g0.y + P0.y, 0.f);
      float m2 = fmaxf(uu + g0.z + P0.z, 0.f), m3 = fmaxf(uu + g0.w + P0.w, 0.f);
      float m4 = fmaxf(uu + g1.x + P1.x, 0.f), m5 = fmaxf(uu + g1.y + P1.y, 0.f);
      float m6 = fmaxf(uu + g1.z + P1.z, 0.f), m7 = fmaxf(uu + g1.w + P1.w, 0.f);
      acc = A0.x * m0 + A0.y * m1 + A0.z * m2 + A0.w * m3
          + A1.x * m4 + A1.y * m5 + A1.z * m6 + A1.w * m7;
      if (WRITE_E) {
        size_t rE = ((size_t)(b * NN + i) * DEE + 16 * s + c_loc) * NN + j0;
        float4 w0; w0.x = m0; w0.y = m1; w0.z = m2; w0.w = m3;
        float4 w1; w1.x = m4; w1.y = m5; w1.z = m6; w1.w = m7;
        *(float4*)&eP[rE] = w0; *(float4*)&eP[rE + 4] = w1;
      }
    }
    // prefetch P/adj/U for i+1 (clamped) — overlaps B + sync
    {
      int in = (i < NN - 1) ? i + 1 : NN - 1;
      size_t rE = ((size_t)(b * NN + in) * DEE + 16 * s + c_loc) * NN + j0;
      P0 = *(const float4*)&eP[rE]; P1 = *(const float4*)&eP[rE + 4];
      size_t rA = (size_t)(b * NN + in) * NN + j0;
      A0 = *(const float4*)&adj[rA]; A1 = *(const float4*)&adj[rA + 4];
      uu = U[(size_t)(b * NN + in) * DEE + 16 * s + c_loc];
    }
    // reduce msum within the 16-thread c-group
    acc += __shfl_down(acc, 8);
    acc += __shfl_down(acc, 4);
    acc += __shfl_down(acc, 2);
    acc += __shfl_down(acc, 1);
    if (jg == 0) msL[c_loc] = acc;
    __syncthreads();   // (2) msL ready

    // ---- Phase B: partial gi from own c-slice (sc1 stores, no fence) ----
    {
      float ms[16];
#pragma unroll
      for (int c = 0; c < 16; ++c) ms[c] = msL[c];
#pragma unroll
      for (int u = 0; u < 6; ++u) {
        int r = tid + (u << 8);
        float pa = 0.f;
#pragma unroll
        for (int c = 0; c < 16; ++c) pa += wihL[c * 1540 + r] * ms[c];
        __hip_atomic_store(&pgb[r], pa, __ATOMIC_RELAXED, __HIP_MEMORY_SCOPE_AGENT);
      }
    }

    // ---- ONE global sync: flag-array barrier (relaxed atomics only) ----
    {
      unsigned tgt = (unsigned)(kround * NN + i + 1);
      __syncthreads();   // (3) vmcnt drain: all sc1 pg stores acked at L3
      if (tid < 64) {
        if (tid == 0)
          __hip_atomic_store(&flags[(((b << 4) + s) << 5)], tgt, __ATOMIC_RELAXED,
                             __HIP_MEMORY_SCOPE_AGENT);
        unsigned* fp = &flags[(((b << 4) + (tid & 15)) << 5)];
        for (;;) {
          unsigned v = __hip_atomic_load(fp, __ATOMIC_RELAXED, __HIP_MEMORY_SCOPE_AGENT);
          if (!__any(v < tgt)) break;
          __builtin_amdgcn_s_sleep(1);
        }
      }
      __syncthreads();   // (4)
    }

    // ---- GRU (replicated): sum 16 partials + bias (sc1 loads) ----
    {
      float sr0 = bi0, sr1 = bi1, sz0 = bi2, sz1 = bi3, sn0 = bi4, sn1 = bi5;
#pragma unroll
      for (int ss = 0; ss < 16; ++ss) {
        float* p = pgr + (size_t)ss * 1536;
        sr0 += __hip_atomic_load(&p[tid],        __ATOMIC_RELAXED, __HIP_MEMORY_SCOPE_AGENT);
        sr1 += __hip_atomic_load(&p[tid + 256],  __ATOMIC_RELAXED, __HIP_MEMORY_SCOPE_AGENT);
        sz0 += __hip_atomic_load(&p[512 + tid],  __ATOMIC_RELAXED, __HIP_MEMORY_SCOPE_AGENT);
        sz1 += __hip_atomic_load(&p[768 + tid],  __ATOMIC_RELAXED, __HIP_MEMORY_SCOPE_AGENT);
        sn0 += __hip_atomic_load(&p[1024 + tid], __ATOMIC_RELAXED, __HIP_MEMORY_SCOPE_AGENT);
        sn1 += __hip_atomic_load(&p[1280 + tid], __ATOMIC_RELAXED, __HIP_MEMORY_SCOPE_AGENT);
      }
      float rg0 = sigmf(sr0 + ghr0), rg1 = sigmf(sr1 + ghr1);
      float z0 = sigmf(sz0 + ghz0),  z1 = sigmf(sz1 + ghz1);
      float nv0 = tanhf_fast(sn0 + rg0 * ghn0);
      float nv1 = tanhf_fast(sn1 + rg1 * ghn1);
      float hn0 = (1.f - z0) * nv0 + z0 * hv0;
      float hn1 = (1.f - z1) * nv1 + z1 * hv1;
      hnL[tid] = hn0; hnL[tid + 256] = hn1;
      size_t rH = (size_t)(b * NN + i) * DVV;
      if ((tid >> 5) == s) h[rH + tid] = hn0;
      if (((tid + 256) >> 5) == s) h[rH + tid + 256] = hn1;
    }
    // prefetch hv/GH for i+1 (clamped) — overlaps C + next A
    {
      int in = (i < NN - 1) ? i + 1 : NN - 1;
      size_t rH = (size_t)(b * NN + in) * DVV;
      hv0 = h[rH + tid]; hv1 = h[rH + tid + 256];
      size_t rG = (size_t)(b * NN + in) * 1536;
      ghr0 = GH[rG + tid]; ghr1 = GH[rG + tid + 256];
      ghz0 = GH[rG + 512 + tid]; ghz1 = GH[rG + 768 + tid];
      ghn0 = GH[rG + 1024 + tid]; ghn1 = GH[rG + 1280 + tid];
    }
    __syncthreads();   // (5) hnL ready

    // ---- Phase C: G[c_loc-slice][i] = W2slice @ h_new ----
    {
      int cw = tid >> 4, dg = tid & 15;
      float acc2 = 0.f;
#pragma unroll
      for (int it = 0; it < 32; ++it) {
        int d = dg + (it << 4);
        acc2 += w2L[cw * 520 + d] * hnL[d];
      }
      acc2 += __shfl_down(acc2, 8);
      acc2 += __shfl_down(acc2, 4);
      acc2 += __shfl_down(acc2, 2);
      acc2 += __shfl_down(acc2, 1);
      if (dg == 0) GL[cw * 132 + i] = acc2;
    }
  }
}

// ---------------- labels ----------------
__global__ __launch_bounds__(128) void k_labels(const float* __restrict__ h, const float* __restrict__ w_ro,
                                                const float* __restrict__ b_ro, float* __restrict__ out) {
  int b = blockIdx.x >> 7, n = blockIdx.x & 127;
  __shared__ __align__(16) float hr[512];
  int tid = threadIdx.x;
  *(float4*)&hr[tid * 4] = *(const float4*)&h[(size_t)((b << 7) + n) * DVV + tid * 4];
  __syncthreads();
  if (tid < NCC) {
    const float* w = w_ro + (size_t)tid * DVV;
    float acc = b_ro[tid];
    for (int d = 0; d < DVV; d += 4) {
      float4 wv = *(const float4*)&w[d];
      acc += wv.x * hr[d] + wv.y * hr[d + 1] + wv.z * hr[d + 2] + wv.w * hr[d + 3];
    }
    out[(size_t)((b << 7) + n) * NCC + tid] = acc;
  }
}

extern "C" void kernel_launch(void* const* d_in, const int* in_sizes, int n_in,
                              void* d_out, int out_size, void* d_ws, size_t ws_size,
                              hipStream_t stream) {
  const float* edge   = (const float*)d_in[0];
  const float* node   = (const float*)d_in[1];
  const float* w_link = (const float*)d_in[6];
  const float* b_link = (const float*)d_in[7];
  const float* w_msg  = (const float*)d_in[8];
  const float* b_msg  = (const float*)d_in[9];
  const float* w_ih   = (const float*)d_in[10];
  const float* w_hh   = (const float*)d_in[11];
  const float* b_ih   = (const float*)d_in[12];
  const float* b_hh   = (const float*)d_in[13];
  const float* w_ro   = (const float*)d_in[14];
  const float* b_ro   = (const float*)d_in[15];
  float* out = (float*)d_out;
  float* ws  = (float*)d_ws;

  // workspace layout (floats)
  float* e_buf  = ws;                      // 33,554,432  (B,N,DE,N)
  float* h_buf  = e_buf + 33554432ull;     //    524,288  (B,N,DV)
  float* GH_buf = h_buf + 524288;          //  1,572,864  (B,N,1536)
  float* U_buf  = GH_buf + 1572864;        //    262,144  (B,N,256)
  float* G_buf  = U_buf + 262144;          //    262,144  (B,N,256)
  float* lE_buf = G_buf + 262144;          //    131,072  (B,N,N)
  float* av_buf = lE_buf + 131072;         //      2,048  (B,2,N)
  float* pg_buf = av_buf + 2048;           //    393,216  (2,B,16,1536) double-buffered
  unsigned* flags = (unsigned*)(pg_buf + 2 * PGOFF);  // 8*16*32 u32 = 4096
  size_t need_bytes = 36710304ull * 4ull;
  if (ws_size < need_bytes) return;

  hipMemsetAsync(flags, 0, 4096 * sizeof(unsigned), stream);
  k_copy<<<512, 256, 0, stream>>>(node, h_buf);

  for (int k = 0; k < 3; ++k) {
    k_av<<<1024, 128, 0, stream>>>(h_buf, w_link, av_buf);
    if (k == 0) k_plogit<1><<<1024, 256, 0, stream>>>(edge, w_msg, w_link, e_buf, lE_buf);
    else        k_plogit<0><<<1024, 256, 0, stream>>>(e_buf, w_msg, w_link, e_buf, lE_buf);
    k_adj<<<512, 256, 0, stream>>>(av_buf, lE_buf, b_link, out);
    k_wh<<<dim3(96, 8), 256, 0, stream>>>(w_hh, 512, 1536, b_hh, h_buf, GH_buf);
    k_wh<<<dim3(16, 8), 256, 0, stream>>>(w_msg, 1280, 256, b_msg, h_buf, U_buf);
    k_wh<<<dim3(16, 8), 256, 0, stream>>>(w_msg + 512, 1280, 256, nullptr, h_buf, G_buf);
    if (k < 2) k_scan5<1><<<dim3(SB, NB), 256, 0, stream>>>(e_buf, out, GH_buf, U_buf, G_buf, h_buf,
                                                            w_ih, b_ih, w_msg, pg_buf, flags, k);
    else       k_scan5<0><<<dim3(SB, NB), 256, 0, stream>>>(e_buf, out, GH_buf, U_buf, G_buf, h_buf,
                                                            w_ih, b_ih, w_msg, pg_buf, flags, k);
  }
  k_labels<<<1024, 128, 0, stream>>>(h_buf, w_ro, b_ro, out + 131072);
}